// Round 7
// baseline (182.550 us; speedup 1.0000x reference)
//
#include <hip/hip_runtime.h>

#define BSZ  8192
#define DDIM 256
#define BM 128
#define BN 128
#define NT   64                  // tiles per dimension
#define NTRI (NT * (NT + 1) / 2) // 2080 upper-triangle tiles
#define NBLK 520                 // simloss blocks (520 * 4 tiles = 2080)

typedef float f32x4 __attribute__((ext_vector_type(4)));
typedef short bf16x8 __attribute__((ext_vector_type(8)));

__device__ __forceinline__ unsigned short f32_to_bf16(float f) {
    unsigned int u = __float_as_uint(f);
    u += 0x7fffu + ((u >> 16) & 1u);   // RNE
    return (unsigned short)(u >> 16);
}

// epilogue constants
#define K_E1   20.60992915555662f    // (1/T)*log2(e)
#define K_E2  -20.60992915555662f
#define K_INVT 14.285714285714286f   // 1/T
#define K_N1   1.4285714285714286f   // 1/(1-0.3)
#define K_N2   0.5714285714285714f   // 0.4/0.7

// ---------------- triangular tile decode (supertile-swizzled) ----------------
__device__ __forceinline__ void decode_tile(int t, int& It, int& Jt) {
    const int off1 = 136, off2 = 392, off3 = 648, off4 = 904, off5 = 1040,
              off6 = 1296, off7 = 1552, off8 = 1688, off9 = 1944;
    int b = (t >= off1) + (t >= off2) + (t >= off3) + (t >= off4) + (t >= off5)
          + (t >= off6) + (t >= off7) + (t >= off8) + (t >= off9);
    int si, sj, r0;
    switch (b) {
        case 0: si = 0; sj = 0; r0 = 0;    break;
        case 1: si = 0; sj = 1; r0 = off1; break;
        case 2: si = 0; sj = 2; r0 = off2; break;
        case 3: si = 0; sj = 3; r0 = off3; break;
        case 4: si = 1; sj = 1; r0 = off4; break;
        case 5: si = 1; sj = 2; r0 = off5; break;
        case 6: si = 1; sj = 3; r0 = off6; break;
        case 7: si = 2; sj = 2; r0 = off7; break;
        case 8: si = 2; sj = 3; r0 = off8; break;
        default: si = 3; sj = 3; r0 = off9; break;
    }
    const int rr = t - r0;
    int il, jl;
    if (si == sj) {
        il = 0;
        #pragma unroll
        for (int q = 1; q < 16; q++) if (rr >= (16 * q - (q * (q - 1)) / 2)) il = q;
        jl = il + (rr - (16 * il - (il * (il - 1)) / 2));
    } else {
        il = rr >> 4;
        jl = rr & 15;
    }
    It = si * 16 + il;
    Jt = sj * 16 + jl;
}

// ---------------- L2-normalize rows; coalesced MFMA-native output; zero posAcc+counter ----------------
// anchorT tile T = C*512 + (row/16), 1 KB each; lane l16 = (row%16)+16*((k%32)/8) holds 8 shorts.
__global__ __launch_bounds__(256) void norm_kernel(const float* __restrict__ feat,
                                                   unsigned short* __restrict__ anchorT,
                                                   float* __restrict__ posAcc,
                                                   unsigned int* __restrict__ counter) {
    __shared__ __align__(16) unsigned short img[32 * 512];   // 32 KB: 32 x 1KB tiles
    const int tid  = threadIdx.x;
    const int wid  = tid >> 6;
    const int lane = tid & 63;
    const int R0   = blockIdx.x * 64;

    posAcc[blockIdx.x * 256 + tid] = 0.0f;                    // 128*256 = 32768 = BSZ*4
    if (blockIdx.x == 0 && tid == 0) *counter = 0u;

    #pragma unroll
    for (int it = 0; it < 16; it++) {
        const int row = R0 + it * 4 + wid;
        const float4 v = ((const float4*)(feat + (size_t)row * DDIM))[lane];
        float ss = v.x * v.x + v.y * v.y + v.z * v.z + v.w * v.w;
        #pragma unroll
        for (int off = 32; off > 0; off >>= 1) ss += __shfl_xor(ss, off, 64);
        const float inv = rsqrtf(ss);
        ushort4 o;
        o.x = f32_to_bf16(v.x * inv);
        o.y = f32_to_bf16(v.y * inv);
        o.z = f32_to_bf16(v.z * inv);
        o.w = f32_to_bf16(v.w * inv);
        const int C    = lane >> 3;
        const int c    = C * 4 + ((row >> 4) & 3);            // local chunk 0..31
        const int l16  = (row & 15) + (((lane >> 1) & 3) << 4);
        *(ushort4*)(&img[c * 512 + l16 * 8 + (lane & 1) * 4]) = o;
    }
    __syncthreads();
    #pragma unroll
    for (int p = 0; p < 8; p++) {
        const int c = p * 4 + wid;                            // chunk 0..31
        const int T = (c >> 2) * 512 + (R0 >> 4) + (c & 3);
        *(bf16x8*)(anchorT + (size_t)T * 512 + lane * 8) = *(const bf16x8*)(&img[c * 512 + lane * 8]);
    }
}

// ---------------- async global -> LDS, 16B/lane ----------------
__device__ __forceinline__ void gload_lds16(const unsigned short* g, unsigned short* l) {
    __builtin_amdgcn_global_load_lds(
        (const __attribute__((address_space(1))) void*)g,
        (__attribute__((address_space(3))) void*)l, 16, 0, 0);
}

// ---------------- fused sim-tile + loss partials: 4 tiles/block, dbuf pipeline ----------------
// part2: float2 {dsum,T2} planes [NT][2][BSZ]; positives -> global atomics posAcc.
__global__ __launch_bounds__(256) void simloss_kernel(
    const unsigned short* __restrict__ anchorT,
    const int* __restrict__ labels,
    float* __restrict__ part,          // float2 [NT][2][BSZ]
    float* __restrict__ posAcc)        // [BSZ][4] {s1, w1, s2corr, cnt}
{
    __shared__ __align__(16) unsigned short As[2][16 * 512];  // 2 x 16 KB
    __shared__ __align__(16) unsigned short Bs[2][16 * 512];  // 2 x 16 KB
    __shared__ int rowLab[2][BM];
    __shared__ int colLab[2][BN];

    const int p    = blockIdx.x;
    const int tid  = threadIdx.x;
    const int wid  = tid >> 6;
    const int lane = tid & 63;
    const int waveM = (wid >> 1) * 64;
    const int waveN = (wid & 1) * 64;
    const int wm4 = waveM >> 4;
    const int wn4 = waveN >> 4;
    const int cl = lane & 15;
    const int rg = lane >> 4;
    const int laneOff = lane * 8;

    int It, Jt;
    decode_tile(p * 4, It, Jt);

    // ---- stage helper (macro to keep addresses in registers, uniform branches) ----
    #define STAGE(ItX, JtX, kcX, slotX)                                              \
        do {                                                                          \
            const int C0s = (kcX) * 2;                                                \
            _Pragma("unroll")                                                         \
            for (int q = 0; q < 4; q++) {                                             \
                const int chunk = wid * 4 + q;                                        \
                const int cq = chunk >> 3;                                            \
                const int Rq = chunk & 7;                                             \
                const size_t at = ((size_t)(C0s + cq) * 512 + (ItX) * 8 + Rq) * 512;  \
                const size_t bt = ((size_t)(C0s + cq) * 512 + (JtX) * 8 + Rq) * 512;  \
                gload_lds16(anchorT + at + laneOff, &As[slotX][chunk * 512]);         \
                gload_lds16(anchorT + bt + laneOff, &Bs[slotX][chunk * 512]);         \
            }                                                                         \
        } while (0)

    #define WRLAB(ItX, JtX, slotX)                                                    \
        do {                                                                          \
            if (tid < BM) rowLab[slotX][tid] = labels[(ItX) * BM + tid];              \
            else          colLab[slotX][tid - BM] = labels[(JtX) * BN + tid - BM];    \
        } while (0)

    STAGE(It, Jt, 0, 0);
    WRLAB(It, Jt, 0);

    #pragma unroll 1
    for (int ti = 0; ti < 4; ++ti) {
        const bool diag  = (It == Jt);
        const bool dwave = diag && (waveM == waveN);
        const int I0 = It * BM, J0 = Jt * BN;
        const int ls = ti & 1;

        int Itn = It, Jtn = Jt;
        if (ti < 3) decode_tile(p * 4 + ti + 1, Itn, Jtn);

        f32x4 c_acc[4][4];
        #pragma unroll
        for (int a = 0; a < 4; a++)
            #pragma unroll
            for (int bq = 0; bq < 4; bq++)
                c_acc[a][bq] = (f32x4){0.f, 0.f, 0.f, 0.f};

        #pragma unroll
        for (int kc = 0; kc < 4; ++kc) {
            __syncthreads();                       // slot (kc&1) staged; prefetch had MFMA-phase to land
            if (kc < 3) {
                STAGE(It, Jt, kc + 1, (kc + 1) & 1);
            } else if (ti < 3) {
                STAGE(Itn, Jtn, 0, 0);
                WRLAB(Itn, Jtn, (ti + 1) & 1);
            }
            const int s = kc & 1;
            #pragma unroll
            for (int ks = 0; ks < 2; ks++) {
                const unsigned short* ab = &As[s][(ks * 8 + wm4) * 512 + laneOff];
                const unsigned short* bb = &Bs[s][(ks * 8 + wn4) * 512 + laneOff];
                const bf16x8 a0 = *(const bf16x8*)(ab);
                const bf16x8 a1 = *(const bf16x8*)(ab + 512);
                const bf16x8 a2 = *(const bf16x8*)(ab + 1024);
                const bf16x8 a3 = *(const bf16x8*)(ab + 1536);
                const bf16x8 b0 = *(const bf16x8*)(bb);
                const bf16x8 b1 = *(const bf16x8*)(bb + 512);
                const bf16x8 b2 = *(const bf16x8*)(bb + 1024);
                const bf16x8 b3 = *(const bf16x8*)(bb + 1536);
                c_acc[0][0] = __builtin_amdgcn_mfma_f32_16x16x32_bf16(a0, b0, c_acc[0][0], 0, 0, 0);
                c_acc[0][1] = __builtin_amdgcn_mfma_f32_16x16x32_bf16(a0, b1, c_acc[0][1], 0, 0, 0);
                c_acc[0][2] = __builtin_amdgcn_mfma_f32_16x16x32_bf16(a0, b2, c_acc[0][2], 0, 0, 0);
                c_acc[0][3] = __builtin_amdgcn_mfma_f32_16x16x32_bf16(a0, b3, c_acc[0][3], 0, 0, 0);
                c_acc[1][0] = __builtin_amdgcn_mfma_f32_16x16x32_bf16(a1, b0, c_acc[1][0], 0, 0, 0);
                c_acc[1][1] = __builtin_amdgcn_mfma_f32_16x16x32_bf16(a1, b1, c_acc[1][1], 0, 0, 0);
                c_acc[1][2] = __builtin_amdgcn_mfma_f32_16x16x32_bf16(a1, b2, c_acc[1][2], 0, 0, 0);
                c_acc[1][3] = __builtin_amdgcn_mfma_f32_16x16x32_bf16(a1, b3, c_acc[1][3], 0, 0, 0);
                c_acc[2][0] = __builtin_amdgcn_mfma_f32_16x16x32_bf16(a2, b0, c_acc[2][0], 0, 0, 0);
                c_acc[2][1] = __builtin_amdgcn_mfma_f32_16x16x32_bf16(a2, b1, c_acc[2][1], 0, 0, 0);
                c_acc[2][2] = __builtin_amdgcn_mfma_f32_16x16x32_bf16(a2, b2, c_acc[2][2], 0, 0, 0);
                c_acc[2][3] = __builtin_amdgcn_mfma_f32_16x16x32_bf16(a2, b3, c_acc[2][3], 0, 0, 0);
                c_acc[3][0] = __builtin_amdgcn_mfma_f32_16x16x32_bf16(a3, b0, c_acc[3][0], 0, 0, 0);
                c_acc[3][1] = __builtin_amdgcn_mfma_f32_16x16x32_bf16(a3, b1, c_acc[3][1], 0, 0, 0);
                c_acc[3][2] = __builtin_amdgcn_mfma_f32_16x16x32_bf16(a3, b2, c_acc[3][2], 0, 0, 0);
                c_acc[3][3] = __builtin_amdgcn_mfma_f32_16x16x32_bf16(a3, b3, c_acc[3][3], 0, 0, 0);
            }
        }

        // ---- epilogue (no barrier): hot path dsum/T2; rare positives -> atomics ----
        int ljr[4], gjr[4];
        #pragma unroll
        for (int fc = 0; fc < 4; fc++) {
            const int cidx = waveN + fc * 16 + cl;
            ljr[fc] = colLab[ls][cidx];
            gjr[fc] = J0 + cidx;
        }
        float cd[4] = {0.f, 0.f, 0.f, 0.f}, ct[4] = {0.f, 0.f, 0.f, 0.f};

        #pragma unroll
        for (int fr = 0; fr < 4; fr++) {
            float rd[4] = {0.f, 0.f, 0.f, 0.f}, rt[4] = {0.f, 0.f, 0.f, 0.f};
            int li[4], gi[4];
            #pragma unroll
            for (int r = 0; r < 4; r++) {
                const int ridx = waveM + fr * 16 + rg * 4 + r;
                li[r] = rowLab[ls][ridx];
                gi[r] = I0 + ridx;
            }
            #pragma unroll
            for (int fc = 0; fc < 4; fc++) {
                const int lj = ljr[fc];
                const f32x4 c = c_acc[fr][fc];
                #pragma unroll
                for (int r = 0; r < 4; r++) {
                    const float s = c[r];
                    const bool self = diag && (fr == fc) && dwave && ((rg * 4 + r) == cl);
                    const float e  = self ? 0.f : exp2f(fmaf(s, K_E1, K_E2));
                    const float wn = fmaxf(fmaf(s, K_N1, K_N2), 1.0f);
                    const float we = wn * e;
                    rd[r] += e;  rt[r] += we;
                    if (!diag) { cd[fc] += e; ct[fc] += we; }
                    if (li[r] == lj && !self) {   // rare (~0.1%)
                        const float wp = fmaxf(1.5f - s, 1.0f);
                        const float slp = fmaf(s, K_INVT, -K_INVT) * wp;
                        float* pi = posAcc + (size_t)gi[r] * 4;
                        atomicAdd(pi + 0, slp);
                        atomicAdd(pi + 1, wp);
                        atomicAdd(pi + 2, we);
                        atomicAdd(pi + 3, 1.0f);
                        if (!diag) {
                            float* pj = posAcc + (size_t)gjr[fc] * 4;
                            atomicAdd(pj + 0, slp);
                            atomicAdd(pj + 1, wp);
                            atomicAdd(pj + 2, we);
                            atomicAdd(pj + 3, 1.0f);
                        }
                    }
                }
            }
            #pragma unroll
            for (int r = 0; r < 4; r++) {
                #pragma unroll
                for (int off = 1; off < 16; off <<= 1) {
                    rd[r] += __shfl_xor(rd[r], off, 64);
                    rt[r] += __shfl_xor(rt[r], off, 64);
                }
            }
            if (cl == 0) {
                const int wh = waveN >> 6;
                float2* dst = (float2*)part + ((size_t)(Jt * 2 + wh)) * BSZ + I0 + waveM + fr * 16 + rg * 4;
                #pragma unroll
                for (int r = 0; r < 4; r++) {
                    float2 v; v.x = rd[r]; v.y = rt[r];
                    dst[r] = v;
                }
            }
        }
        if (!diag) {
            #pragma unroll
            for (int fc = 0; fc < 4; fc++) {
                cd[fc] += __shfl_xor(cd[fc], 16, 64);
                cd[fc] += __shfl_xor(cd[fc], 32, 64);
                ct[fc] += __shfl_xor(ct[fc], 16, 64);
                ct[fc] += __shfl_xor(ct[fc], 32, 64);
            }
            if (rg == 0) {
                const int wmh = waveM >> 6;
                float2* dst = (float2*)part + ((size_t)(It * 2 + wmh)) * BSZ + J0 + waveN + cl;
                #pragma unroll
                for (int fc = 0; fc < 4; fc++) {
                    float2 v; v.x = cd[fc]; v.y = ct[fc];
                    dst[fc * 16] = v;
                }
            }
        }

        It = Itn; Jt = Jtn;
    }
    #undef STAGE
    #undef WRLAB
}

// ---------------- per-row combine + grid-wide final (done-counter) ----------------
__global__ __launch_bounds__(256) void reduce_final_kernel(
    const float* __restrict__ part, const float* __restrict__ posAcc,
    double* __restrict__ partial, unsigned int* __restrict__ counter,
    float* __restrict__ out)
{
    const int i = blockIdx.x * 256 + threadIdx.x;
    float dsum = 0.f, T2 = 0.f;
    const float2* p2 = (const float2*)part;
    #pragma unroll 4
    for (int j = 0; j < NT * 2; j++) {
        const float2 v = p2[(size_t)j * BSZ + i];
        dsum += v.x; T2 += v.y;
    }
    const float4 pa = ((const float4*)posAcc)[i];   // {s1, w1, s2corr, cnt}
    const float s1 = pa.x, w1 = pa.y, s2 = T2 - pa.z, cnt = pa.w;
    const float pc = fmaxf(cnt, 1.0f);
    const float nc = fmaxf(8191.0f - cnt, 1.0f);
    const float ld = logf(dsum);
    const double pos_i = (double)((s1 - ld * w1) / pc);
    const double neg_i = (double)((s2 / dsum) / nc);

    __shared__ double sp[256], sn[256];
    sp[threadIdx.x] = pos_i; sn[threadIdx.x] = neg_i;
    __syncthreads();
    for (int s = 128; s > 0; s >>= 1) {
        if (threadIdx.x < s) {
            sp[threadIdx.x] += sp[threadIdx.x + s];
            sn[threadIdx.x] += sn[threadIdx.x + s];
        }
        __syncthreads();
    }
    __shared__ bool amLast;
    if (threadIdx.x == 0) {
        partial[blockIdx.x * 2 + 0] = sp[0];
        partial[blockIdx.x * 2 + 1] = sn[0];
        __threadfence();
        amLast = (atomicAdd(counter, 1u) == 31u);
    }
    __syncthreads();
    if (amLast) {
        __threadfence();
        const int lane = threadIdx.x;
        double p = 0.0, n = 0.0;
        if (lane < 32) {
            volatile double* vp = (volatile double*)partial;
            p = vp[lane * 2 + 0];
            n = vp[lane * 2 + 1];
        }
        #pragma unroll
        for (int o = 32; o > 0; o >>= 1) { p += __shfl_xor(p, o, 64); n += __shfl_xor(n, o, 64); }
        if (lane == 0) out[0] = (float)(-p / (double)BSZ + 0.3 * (n / (double)BSZ));
    }
}

extern "C" void kernel_launch(void* const* d_in, const int* in_sizes, int n_in,
                              void* d_out, int out_size, void* d_ws, size_t ws_size,
                              hipStream_t stream) {
    const float* feat = (const float*)d_in[0];
    const int* labels = (const int*)d_in[1];
    float* out = (float*)d_out;

    char* ws = (char*)d_ws;
    unsigned short* anchorT = (unsigned short*)ws;                       // 4 MB MFMA-native
    const size_t anchorBytes = (size_t)BSZ * DDIM * sizeof(unsigned short);
    float* part = (float*)(ws + anchorBytes);                            // 64*2*8192 float2 = 8.4 MB
    const size_t partBytes = (size_t)NT * 2 * BSZ * 2 * sizeof(float);
    float* posAcc = (float*)(ws + anchorBytes + partBytes);              // 128 KB
    const size_t posBytes = (size_t)BSZ * 4 * sizeof(float);
    double* partial = (double*)(ws + anchorBytes + partBytes + posBytes); // 512 B
    unsigned int* counter = (unsigned int*)(ws + anchorBytes + partBytes + posBytes + 512);

    norm_kernel<<<BSZ / 64, 256, 0, stream>>>(feat, anchorT, posAcc, counter);
    simloss_kernel<<<NBLK, 256, 0, stream>>>(anchorT, labels, part, posAcc);
    reduce_final_kernel<<<BSZ / 256, 256, 0, stream>>>(part, posAcc, partial, counter, out);
}

// Round 8
// 125.060 us; speedup vs baseline: 1.4597x; 1.4597x over previous
//
#include <hip/hip_runtime.h>

#define BSZ  8192
#define DDIM 256
#define BM 128
#define BN 128
#define NT   64                  // tiles per dimension
#define NTRI (NT * (NT + 1) / 2) // 2080 upper-triangle tiles

typedef float f32x4 __attribute__((ext_vector_type(4)));
typedef short bf16x8 __attribute__((ext_vector_type(8)));

__device__ __forceinline__ unsigned short f32_to_bf16(float f) {
    unsigned int u = __float_as_uint(f);
    u += 0x7fffu + ((u >> 16) & 1u);   // RNE
    return (unsigned short)(u >> 16);
}

// epilogue constants
#define K_E1   20.60992915555662f    // (1/T)*log2(e)
#define K_E2  -20.60992915555662f
#define K_INVT 14.285714285714286f   // 1/T
#define K_N1   1.4285714285714286f   // 1/(1-0.3)
#define K_N2   0.5714285714285714f   // 0.4/0.7

// ---------------- triangular tile decode (supertile-swizzled) ----------------
__device__ __forceinline__ void decode_tile(int t, int& It, int& Jt) {
    const int off1 = 136, off2 = 392, off3 = 648, off4 = 904, off5 = 1040,
              off6 = 1296, off7 = 1552, off8 = 1688, off9 = 1944;
    int b = (t >= off1) + (t >= off2) + (t >= off3) + (t >= off4) + (t >= off5)
          + (t >= off6) + (t >= off7) + (t >= off8) + (t >= off9);
    int si, sj, r0;
    switch (b) {
        case 0: si = 0; sj = 0; r0 = 0;    break;
        case 1: si = 0; sj = 1; r0 = off1; break;
        case 2: si = 0; sj = 2; r0 = off2; break;
        case 3: si = 0; sj = 3; r0 = off3; break;
        case 4: si = 1; sj = 1; r0 = off4; break;
        case 5: si = 1; sj = 2; r0 = off5; break;
        case 6: si = 1; sj = 3; r0 = off6; break;
        case 7: si = 2; sj = 2; r0 = off7; break;
        case 8: si = 2; sj = 3; r0 = off8; break;
        default: si = 3; sj = 3; r0 = off9; break;
    }
    const int rr = t - r0;
    int il, jl;
    if (si == sj) {
        il = 0;
        #pragma unroll
        for (int q = 1; q < 16; q++) if (rr >= (16 * q - (q * (q - 1)) / 2)) il = q;
        jl = il + (rr - (16 * il - (il * (il - 1)) / 2));
    } else {
        il = rr >> 4;
        jl = rr & 15;
    }
    It = si * 16 + il;
    Jt = sj * 16 + jl;
}

// ---------------- L2-normalize rows; coalesced MFMA-native output; zero posAcc+counter ----------------
// anchorT tile T = C*512 + (row/16), 1 KB each; lane l16 = (row%16)+16*((k%32)/8) holds 8 shorts.
__global__ __launch_bounds__(256) void norm_kernel(const float* __restrict__ feat,
                                                   unsigned short* __restrict__ anchorT,
                                                   float* __restrict__ posAcc,
                                                   unsigned int* __restrict__ counter) {
    __shared__ __align__(16) unsigned short img[32 * 512];   // 32 KB: 32 x 1KB tiles
    const int tid  = threadIdx.x;
    const int wid  = tid >> 6;
    const int lane = tid & 63;
    const int R0   = blockIdx.x * 64;

    posAcc[blockIdx.x * 256 + tid] = 0.0f;                    // 128*256 = 32768 = BSZ*4
    if (blockIdx.x == 0 && tid == 0) *counter = 0u;

    #pragma unroll
    for (int it = 0; it < 16; it++) {
        const int row = R0 + it * 4 + wid;
        const float4 v = ((const float4*)(feat + (size_t)row * DDIM))[lane];
        float ss = v.x * v.x + v.y * v.y + v.z * v.z + v.w * v.w;
        #pragma unroll
        for (int off = 32; off > 0; off >>= 1) ss += __shfl_xor(ss, off, 64);
        const float inv = rsqrtf(ss);
        ushort4 o;
        o.x = f32_to_bf16(v.x * inv);
        o.y = f32_to_bf16(v.y * inv);
        o.z = f32_to_bf16(v.z * inv);
        o.w = f32_to_bf16(v.w * inv);
        const int C    = lane >> 3;
        const int c    = C * 4 + ((row >> 4) & 3);            // local chunk 0..31
        const int l16  = (row & 15) + (((lane >> 1) & 3) << 4);
        *(ushort4*)(&img[c * 512 + l16 * 8 + (lane & 1) * 4]) = o;
    }
    __syncthreads();
    #pragma unroll
    for (int p = 0; p < 8; p++) {
        const int c = p * 4 + wid;                            // chunk 0..31
        const int T = (c >> 2) * 512 + (R0 >> 4) + (c & 3);
        *(bf16x8*)(anchorT + (size_t)T * 512 + lane * 8) = *(const bf16x8*)(&img[c * 512 + lane * 8]);
    }
}

// ---------------- async global -> LDS, 16B/lane ----------------
__device__ __forceinline__ void gload_lds16(const unsigned short* g, unsigned short* l) {
    __builtin_amdgcn_global_load_lds(
        (const __attribute__((address_space(1))) void*)g,
        (__attribute__((address_space(3))) void*)l, 16, 0, 0);
}

// ---------------- fused sim-tile + loss partials (upper triangle) ----------------
// 512 threads / 8 waves; wave = 64x32 sub-tile (32 AGPR acc). BK=128, single-buffer.
// part: float2 {dsum,T2} plane [NT][BSZ]; rare positives -> global atomics posAcc.
__global__ __launch_bounds__(512) void simloss_kernel(
    const unsigned short* __restrict__ anchorT,
    const int* __restrict__ labels,
    float* __restrict__ part,          // float2 [NT][BSZ]
    float* __restrict__ posAcc)        // [BSZ][4] {s1, w1, s2corr, cnt}
{
    __shared__ __align__(16) unsigned short As[32 * 512];  // 32 KB (128 rows x 128 k)
    __shared__ __align__(16) unsigned short Bs[32 * 512];  // 32 KB
    __shared__ float rowDT[4][BM][2];                      // per col-group partials, 4 KB
    __shared__ float colDT[2][BN][2];                      // per row-group partials, 2 KB
    __shared__ int rowLab[BM];
    __shared__ int colLab[BN];

    int It, Jt;
    decode_tile(blockIdx.x, It, Jt);
    const bool diag = (It == Jt);
    const int I0 = It * BM, J0 = Jt * BN;

    const int tid  = threadIdx.x;
    const int lane = tid & 63;
    const int w    = tid >> 6;       // 0..7
    const int rw   = w >> 2;         // row-group: rows rw*64..+63
    const int cw   = w & 3;          // col-group: cols cw*32..+31
    const int cl   = lane & 15;
    const int rg   = lane >> 4;
    const int laneOff = lane * 8;    // shorts (16 B)

    if (tid < BM) rowLab[tid] = labels[I0 + tid];
    else if (tid < 2 * BM) colLab[tid - BM] = labels[J0 + tid - BM];

    f32x4 acc[4][2];
    #pragma unroll
    for (int f = 0; f < 4; f++)
        #pragma unroll
        for (int g = 0; g < 2; g++)
            acc[f][g] = (f32x4){0.f, 0.f, 0.f, 0.f};

    #pragma unroll
    for (int kc = 0; kc < 2; kc++) {
        // stage 64 KB: 4 A-instrs + 4 B-instrs, each 8 KB (512 threads x 16 B)
        #pragma unroll
        for (int i = 0; i < 4; i++) {
            const int C = kc * 4 + i;                          // k/32 chunk column
            const size_t ga = ((size_t)C * 512 + It * 8) * 512;
            const size_t gb = ((size_t)C * 512 + Jt * 8) * 512;
            gload_lds16(anchorT + ga + tid * 8, &As[i * 4096 + tid * 8 - laneOff]);
            gload_lds16(anchorT + gb + tid * 8, &Bs[i * 4096 + tid * 8 - laneOff]);
        }
        __syncthreads();
        #pragma unroll
        for (int ks = 0; ks < 4; ks++) {
            const unsigned short* aB = &As[(ks * 8 + rw * 4) * 512 + laneOff];
            const unsigned short* bB = &Bs[(ks * 8 + cw * 2) * 512 + laneOff];
            const bf16x8 a0 = *(const bf16x8*)(aB);
            const bf16x8 a1 = *(const bf16x8*)(aB + 512);
            const bf16x8 a2 = *(const bf16x8*)(aB + 1024);
            const bf16x8 a3 = *(const bf16x8*)(aB + 1536);
            const bf16x8 b0 = *(const bf16x8*)(bB);
            const bf16x8 b1 = *(const bf16x8*)(bB + 512);
            acc[0][0] = __builtin_amdgcn_mfma_f32_16x16x32_bf16(a0, b0, acc[0][0], 0, 0, 0);
            acc[0][1] = __builtin_amdgcn_mfma_f32_16x16x32_bf16(a0, b1, acc[0][1], 0, 0, 0);
            acc[1][0] = __builtin_amdgcn_mfma_f32_16x16x32_bf16(a1, b0, acc[1][0], 0, 0, 0);
            acc[1][1] = __builtin_amdgcn_mfma_f32_16x16x32_bf16(a1, b1, acc[1][1], 0, 0, 0);
            acc[2][0] = __builtin_amdgcn_mfma_f32_16x16x32_bf16(a2, b0, acc[2][0], 0, 0, 0);
            acc[2][1] = __builtin_amdgcn_mfma_f32_16x16x32_bf16(a2, b1, acc[2][1], 0, 0, 0);
            acc[3][0] = __builtin_amdgcn_mfma_f32_16x16x32_bf16(a3, b0, acc[3][0], 0, 0, 0);
            acc[3][1] = __builtin_amdgcn_mfma_f32_16x16x32_bf16(a3, b1, acc[3][1], 0, 0, 0);
        }
        __syncthreads();   // reads done before restaging (kc=0) / before epilogue partial writes (kc=1)
    }

    // ---- epilogue: hot path dsum/T2; rare positives -> atomics ----
    int ljr[2], gjr[2];
    #pragma unroll
    for (int g = 0; g < 2; g++) {
        const int cidx = cw * 32 + g * 16 + cl;
        ljr[g] = colLab[cidx];
        gjr[g] = J0 + cidx;
    }
    float cd[2] = {0.f, 0.f}, ct[2] = {0.f, 0.f};

    #pragma unroll
    for (int f = 0; f < 4; f++) {
        float rd[4] = {0.f, 0.f, 0.f, 0.f}, rt[4] = {0.f, 0.f, 0.f, 0.f};
        int li[4], gi[4];
        #pragma unroll
        for (int r = 0; r < 4; r++) {
            const int ridx = rw * 64 + f * 16 + rg * 4 + r;
            li[r] = rowLab[ridx];
            gi[r] = I0 + ridx;
        }
        #pragma unroll
        for (int g = 0; g < 2; g++) {
            const int lj = ljr[g];
            const bool granule = (rw * 4 + f) == (cw * 2 + g);   // 16x16 block on the diagonal
            const f32x4 c = acc[f][g];
            #pragma unroll
            for (int r = 0; r < 4; r++) {
                const float s = c[r];
                const bool self = diag && granule && ((rg * 4 + r) == cl);
                const float e  = self ? 0.f : exp2f(fmaf(s, K_E1, K_E2));
                const float wn = fmaxf(fmaf(s, K_N1, K_N2), 1.0f);
                const float we = wn * e;
                rd[r] += e;  rt[r] += we;
                if (!diag) { cd[g] += e; ct[g] += we; }
                if (li[r] == lj && !self) {   // rare (~0.1%)
                    const float wp = fmaxf(1.5f - s, 1.0f);
                    const float slp = fmaf(s, K_INVT, -K_INVT) * wp;
                    float* pi = posAcc + (size_t)gi[r] * 4;
                    atomicAdd(pi + 0, slp);
                    atomicAdd(pi + 1, wp);
                    atomicAdd(pi + 2, we);
                    atomicAdd(pi + 3, 1.0f);
                    if (!diag) {
                        float* pj = posAcc + (size_t)gjr[g] * 4;
                        atomicAdd(pj + 0, slp);
                        atomicAdd(pj + 1, wp);
                        atomicAdd(pj + 2, we);
                        atomicAdd(pj + 3, 1.0f);
                    }
                }
            }
        }
        #pragma unroll
        for (int r = 0; r < 4; r++) {
            #pragma unroll
            for (int off = 1; off < 16; off <<= 1) {
                rd[r] += __shfl_xor(rd[r], off, 64);
                rt[r] += __shfl_xor(rt[r], off, 64);
            }
        }
        if (cl == 0) {
            #pragma unroll
            for (int r = 0; r < 4; r++) {
                const int row = rw * 64 + f * 16 + rg * 4 + r;
                rowDT[cw][row][0] = rd[r];
                rowDT[cw][row][1] = rt[r];
            }
        }
    }
    if (!diag) {
        #pragma unroll
        for (int g = 0; g < 2; g++) {
            cd[g] += __shfl_xor(cd[g], 16, 64);
            cd[g] += __shfl_xor(cd[g], 32, 64);
            ct[g] += __shfl_xor(ct[g], 16, 64);
            ct[g] += __shfl_xor(ct[g], 32, 64);
        }
        if (rg == 0) {
            #pragma unroll
            for (int g = 0; g < 2; g++) {
                const int col = cw * 32 + g * 16 + cl;
                colDT[rw][col][0] = cd[g];
                colDT[rw][col][1] = ct[g];
            }
        }
    }

    __syncthreads();
    if (tid < BM) {
        float2 v;
        v.x = rowDT[0][tid][0] + rowDT[1][tid][0] + rowDT[2][tid][0] + rowDT[3][tid][0];
        v.y = rowDT[0][tid][1] + rowDT[1][tid][1] + rowDT[2][tid][1] + rowDT[3][tid][1];
        ((float2*)part)[(size_t)Jt * BSZ + I0 + tid] = v;
    } else if (tid < 2 * BM && !diag) {
        const int c = tid - BM;
        float2 v;
        v.x = colDT[0][c][0] + colDT[1][c][0];
        v.y = colDT[0][c][1] + colDT[1][c][1];
        ((float2*)part)[(size_t)It * BSZ + J0 + c] = v;
    }
}

// ---------------- per-row combine + grid-wide final (done-counter) ----------------
__global__ __launch_bounds__(256) void reduce_final_kernel(
    const float* __restrict__ part, const float* __restrict__ posAcc,
    double* __restrict__ partial, unsigned int* __restrict__ counter,
    float* __restrict__ out)
{
    const int i = blockIdx.x * 256 + threadIdx.x;
    float dsum = 0.f, T2 = 0.f;
    const float2* p2 = (const float2*)part;
    #pragma unroll 8
    for (int j = 0; j < NT; j++) {
        const float2 v = p2[(size_t)j * BSZ + i];
        dsum += v.x; T2 += v.y;
    }
    const float4 pa = ((const float4*)posAcc)[i];   // {s1, w1, s2corr, cnt}
    const float s1 = pa.x, w1 = pa.y, s2 = T2 - pa.z, cnt = pa.w;
    const float pc = fmaxf(cnt, 1.0f);
    const float nc = fmaxf(8191.0f - cnt, 1.0f);
    const float ld = logf(dsum);
    const double pos_i = (double)((s1 - ld * w1) / pc);
    const double neg_i = (double)((s2 / dsum) / nc);

    __shared__ double sp[256], sn[256];
    sp[threadIdx.x] = pos_i; sn[threadIdx.x] = neg_i;
    __syncthreads();
    for (int s = 128; s > 0; s >>= 1) {
        if (threadIdx.x < s) {
            sp[threadIdx.x] += sp[threadIdx.x + s];
            sn[threadIdx.x] += sn[threadIdx.x + s];
        }
        __syncthreads();
    }
    __shared__ bool amLast;
    if (threadIdx.x == 0) {
        partial[blockIdx.x * 2 + 0] = sp[0];
        partial[blockIdx.x * 2 + 1] = sn[0];
        __threadfence();
        amLast = (atomicAdd(counter, 1u) == 31u);
    }
    __syncthreads();
    if (amLast) {
        __threadfence();
        const int lane = threadIdx.x;
        double p = 0.0, n = 0.0;
        if (lane < 32) {
            volatile double* vp = (volatile double*)partial;
            p = vp[lane * 2 + 0];
            n = vp[lane * 2 + 1];
        }
        #pragma unroll
        for (int o = 32; o > 0; o >>= 1) { p += __shfl_xor(p, o, 64); n += __shfl_xor(n, o, 64); }
        if (lane == 0) out[0] = (float)(-p / (double)BSZ + 0.3 * (n / (double)BSZ));
    }
}

extern "C" void kernel_launch(void* const* d_in, const int* in_sizes, int n_in,
                              void* d_out, int out_size, void* d_ws, size_t ws_size,
                              hipStream_t stream) {
    const float* feat = (const float*)d_in[0];
    const int* labels = (const int*)d_in[1];
    float* out = (float*)d_out;

    char* ws = (char*)d_ws;
    unsigned short* anchorT = (unsigned short*)ws;                       // 4 MB MFMA-native
    const size_t anchorBytes = (size_t)BSZ * DDIM * sizeof(unsigned short);
    float* part = (float*)(ws + anchorBytes);                            // 64*8192 float2 = 4 MB
    const size_t partBytes = (size_t)NT * BSZ * 2 * sizeof(float);
    float* posAcc = (float*)(ws + anchorBytes + partBytes);              // 128 KB
    const size_t posBytes = (size_t)BSZ * 4 * sizeof(float);
    double* partial = (double*)(ws + anchorBytes + partBytes + posBytes); // 512 B
    unsigned int* counter = (unsigned int*)(ws + anchorBytes + partBytes + posBytes + 512);

    norm_kernel<<<BSZ / 64, 256, 0, stream>>>(feat, anchorT, posAcc, counter);
    simloss_kernel<<<NTRI, 512, 0, stream>>>(anchorT, labels, part, posAcc);
    reduce_final_kernel<<<BSZ / 256, 256, 0, stream>>>(part, posAcc, partial, counter, out);
}

// Round 9
// 117.320 us; speedup vs baseline: 1.5560x; 1.0660x over previous
//
#include <hip/hip_runtime.h>

#define BSZ  8192
#define DDIM 256
#define BM 128
#define BN 128
#define NT   64                  // tiles per dimension
#define NTRI (NT * (NT + 1) / 2) // 2080 upper-triangle tiles

typedef float f32x4 __attribute__((ext_vector_type(4)));
typedef short bf16x8 __attribute__((ext_vector_type(8)));

__device__ __forceinline__ unsigned short f32_to_bf16(float f) {
    unsigned int u = __float_as_uint(f);
    u += 0x7fffu + ((u >> 16) & 1u);   // RNE
    return (unsigned short)(u >> 16);
}

// epilogue constants
#define K_E1   20.60992915555662f    // (1/T)*log2(e)
#define K_E2  -20.60992915555662f
#define K_INVT 14.285714285714286f   // 1/T
#define K_N1   1.4285714285714286f   // 1/(1-0.3)
#define K_N2   0.5714285714285714f   // 0.4/0.7

// ---------------- triangular tile decode (supertile-swizzled) ----------------
__device__ __forceinline__ void decode_tile(int t, int& It, int& Jt) {
    const int off1 = 136, off2 = 392, off3 = 648, off4 = 904, off5 = 1040,
              off6 = 1296, off7 = 1552, off8 = 1688, off9 = 1944;
    int b = (t >= off1) + (t >= off2) + (t >= off3) + (t >= off4) + (t >= off5)
          + (t >= off6) + (t >= off7) + (t >= off8) + (t >= off9);
    int si, sj, r0;
    switch (b) {
        case 0: si = 0; sj = 0; r0 = 0;    break;
        case 1: si = 0; sj = 1; r0 = off1; break;
        case 2: si = 0; sj = 2; r0 = off2; break;
        case 3: si = 0; sj = 3; r0 = off3; break;
        case 4: si = 1; sj = 1; r0 = off4; break;
        case 5: si = 1; sj = 2; r0 = off5; break;
        case 6: si = 1; sj = 3; r0 = off6; break;
        case 7: si = 2; sj = 2; r0 = off7; break;
        case 8: si = 2; sj = 3; r0 = off8; break;
        default: si = 3; sj = 3; r0 = off9; break;
    }
    const int rr = t - r0;
    int il, jl;
    if (si == sj) {
        il = 0;
        #pragma unroll
        for (int q = 1; q < 16; q++) if (rr >= (16 * q - (q * (q - 1)) / 2)) il = q;
        jl = il + (rr - (16 * il - (il * (il - 1)) / 2));
    } else {
        il = rr >> 4;
        jl = rr & 15;
    }
    It = si * 16 + il;
    Jt = sj * 16 + jl;
}

// ---------------- L2-normalize rows; coalesced MFMA-native output; zero posAcc+counter ----------------
// anchorT tile T = C*512 + (row/16), 1 KB each; lane l16 = (row%16)+16*((k%32)/8) holds 8 shorts.
__global__ __launch_bounds__(256) void norm_kernel(const float* __restrict__ feat,
                                                   unsigned short* __restrict__ anchorT,
                                                   float* __restrict__ posAcc,
                                                   unsigned int* __restrict__ counter) {
    __shared__ __align__(16) unsigned short img[32 * 512];   // 32 KB: 32 x 1KB tiles
    const int tid  = threadIdx.x;
    const int wid  = tid >> 6;
    const int lane = tid & 63;
    const int R0   = blockIdx.x * 64;

    posAcc[blockIdx.x * 256 + tid] = 0.0f;                    // 128*256 = 32768 = BSZ*4
    if (blockIdx.x == 0 && tid == 0) *counter = 0u;

    #pragma unroll
    for (int it = 0; it < 16; it++) {
        const int row = R0 + it * 4 + wid;
        const float4 v = ((const float4*)(feat + (size_t)row * DDIM))[lane];
        float ss = v.x * v.x + v.y * v.y + v.z * v.z + v.w * v.w;
        #pragma unroll
        for (int off = 32; off > 0; off >>= 1) ss += __shfl_xor(ss, off, 64);
        const float inv = rsqrtf(ss);
        ushort4 o;
        o.x = f32_to_bf16(v.x * inv);
        o.y = f32_to_bf16(v.y * inv);
        o.z = f32_to_bf16(v.z * inv);
        o.w = f32_to_bf16(v.w * inv);
        const int C    = lane >> 3;
        const int c    = C * 4 + ((row >> 4) & 3);            // local chunk 0..31
        const int l16  = (row & 15) + (((lane >> 1) & 3) << 4);
        *(ushort4*)(&img[c * 512 + l16 * 8 + (lane & 1) * 4]) = o;
    }
    __syncthreads();
    #pragma unroll
    for (int p = 0; p < 8; p++) {
        const int c = p * 4 + wid;                            // chunk 0..31
        const int T = (c >> 2) * 512 + (R0 >> 4) + (c & 3);
        *(bf16x8*)(anchorT + (size_t)T * 512 + lane * 8) = *(const bf16x8*)(&img[c * 512 + lane * 8]);
    }
}

// ---------------- async global -> LDS, 16B/lane ----------------
__device__ __forceinline__ void gload_lds16(const unsigned short* g, unsigned short* l) {
    __builtin_amdgcn_global_load_lds(
        (const __attribute__((address_space(1))) void*)g,
        (__attribute__((address_space(3))) void*)l, 16, 0, 0);
}

// ---------------- fused sim-tile + loss partials (upper triangle) ----------------
// 512 threads / 8 waves; wave = 32x64 sub-tile (2 A-frag x 4 B-frag, 32 AGPR acc).
// BK=64, single-buffer, ~39 KB LDS -> 4 blocks/CU for cross-block phase overlap.
// part: float2 {dsum,T2} plane [NT][BSZ]; rare positives -> global atomics posAcc.
__global__ __launch_bounds__(512) void simloss_kernel(
    const unsigned short* __restrict__ anchorT,
    const int* __restrict__ labels,
    float* __restrict__ part,          // float2 [NT][BSZ]
    float* __restrict__ posAcc)        // [BSZ][4] {s1, w1, s2corr, cnt}
{
    __shared__ __align__(16) unsigned short As[8 * 512];   // 8 KB  wait-sized below
    __shared__ __align__(16) unsigned short As2[8 * 512];
    __shared__ __align__(16) unsigned short Bs[8 * 512];
    __shared__ __align__(16) unsigned short Bs2[8 * 512];
    __shared__ float rowDT[2][BM][2];                      // per col-group partials, 2 KB
    __shared__ float colDT[4][BN][2];                      // per row-group partials, 4 KB
    __shared__ int rowLab[BM];
    __shared__ int colLab[BN];

    int It, Jt;
    decode_tile(blockIdx.x, It, Jt);
    const bool diag = (It == Jt);
    const int I0 = It * BM, J0 = Jt * BN;

    const int tid  = threadIdx.x;
    const int lane = tid & 63;
    const int w    = tid >> 6;       // 0..7
    const int rw   = w >> 1;         // row-group: rows rw*32..+31
    const int cw   = w & 1;          // col-group: cols cw*64..+63
    const int cl   = lane & 15;
    const int rg   = lane >> 4;
    const int laneOff = lane * 8;    // shorts (16 B)

    if (tid < BM) rowLab[tid] = labels[I0 + tid];
    else if (tid < 2 * BM) colLab[tid - BM] = labels[J0 + tid - BM];

    f32x4 acc[2][4];
    #pragma unroll
    for (int f = 0; f < 2; f++)
        #pragma unroll
        for (int g = 0; g < 4; g++)
            acc[f][g] = (f32x4){0.f, 0.f, 0.f, 0.f};

    #pragma unroll
    for (int kc = 0; kc < 4; kc++) {
        // stage 32 KB: chunk columns C = kc*2 + {0,1}; each 8 KB (512 thr x 16 B)
        {
            const int C0 = kc * 2;
            const size_t ga0 = ((size_t)C0 * 512 + It * 8) * 512;
            const size_t gb0 = ((size_t)C0 * 512 + Jt * 8) * 512;
            const size_t ga1 = ((size_t)(C0 + 1) * 512 + It * 8) * 512;
            const size_t gb1 = ((size_t)(C0 + 1) * 512 + Jt * 8) * 512;
            gload_lds16(anchorT + ga0 + tid * 8, &As[w * 512]);
            gload_lds16(anchorT + gb0 + tid * 8, &Bs[w * 512]);
            gload_lds16(anchorT + ga1 + tid * 8, &As2[w * 512]);
            gload_lds16(anchorT + gb1 + tid * 8, &Bs2[w * 512]);
        }
        __syncthreads();
        #pragma unroll
        for (int ks = 0; ks < 2; ks++) {
            const unsigned short* aB = (ks == 0 ? As : As2) + (rw * 2) * 512 + laneOff;
            const unsigned short* bB = (ks == 0 ? Bs : Bs2) + (cw * 4) * 512 + laneOff;
            const bf16x8 a0 = *(const bf16x8*)(aB);
            const bf16x8 a1 = *(const bf16x8*)(aB + 512);
            const bf16x8 b0 = *(const bf16x8*)(bB);
            const bf16x8 b1 = *(const bf16x8*)(bB + 512);
            const bf16x8 b2 = *(const bf16x8*)(bB + 1024);
            const bf16x8 b3 = *(const bf16x8*)(bB + 1536);
            acc[0][0] = __builtin_amdgcn_mfma_f32_16x16x32_bf16(a0, b0, acc[0][0], 0, 0, 0);
            acc[0][1] = __builtin_amdgcn_mfma_f32_16x16x32_bf16(a0, b1, acc[0][1], 0, 0, 0);
            acc[0][2] = __builtin_amdgcn_mfma_f32_16x16x32_bf16(a0, b2, acc[0][2], 0, 0, 0);
            acc[0][3] = __builtin_amdgcn_mfma_f32_16x16x32_bf16(a0, b3, acc[0][3], 0, 0, 0);
            acc[1][0] = __builtin_amdgcn_mfma_f32_16x16x32_bf16(a1, b0, acc[1][0], 0, 0, 0);
            acc[1][1] = __builtin_amdgcn_mfma_f32_16x16x32_bf16(a1, b1, acc[1][1], 0, 0, 0);
            acc[1][2] = __builtin_amdgcn_mfma_f32_16x16x32_bf16(a1, b2, acc[1][2], 0, 0, 0);
            acc[1][3] = __builtin_amdgcn_mfma_f32_16x16x32_bf16(a1, b3, acc[1][3], 0, 0, 0);
        }
        __syncthreads();   // all reads done before restage / epilogue LDS writes
    }

    // ---- epilogue: hot path dsum/T2; rare positives -> atomics ----
    int ljr[4], gjr[4];
    #pragma unroll
    for (int g = 0; g < 4; g++) {
        const int cidx = cw * 64 + g * 16 + cl;
        ljr[g] = colLab[cidx];
        gjr[g] = J0 + cidx;
    }
    float cd[4] = {0.f, 0.f, 0.f, 0.f}, ct[4] = {0.f, 0.f, 0.f, 0.f};

    #pragma unroll
    for (int f = 0; f < 2; f++) {
        float rd[4] = {0.f, 0.f, 0.f, 0.f}, rt[4] = {0.f, 0.f, 0.f, 0.f};
        int li[4], gi[4];
        #pragma unroll
        for (int r = 0; r < 4; r++) {
            const int ridx = rw * 32 + f * 16 + rg * 4 + r;
            li[r] = rowLab[ridx];
            gi[r] = I0 + ridx;
        }
        #pragma unroll
        for (int g = 0; g < 4; g++) {
            const int lj = ljr[g];
            const bool granule = (rw * 2 + f) == (cw * 4 + g);   // 16x16 block on tile diagonal
            const f32x4 c = acc[f][g];
            #pragma unroll
            for (int r = 0; r < 4; r++) {
                const float s = c[r];
                const bool self = diag && granule && ((rg * 4 + r) == cl);
                const float e  = self ? 0.f : exp2f(fmaf(s, K_E1, K_E2));
                const float wn = fmaxf(fmaf(s, K_N1, K_N2), 1.0f);
                const float we = wn * e;
                rd[r] += e;  rt[r] += we;
                if (!diag) { cd[g] += e; ct[g] += we; }
                if (li[r] == lj && !self) {   // rare (~0.1%)
                    const float wp = fmaxf(1.5f - s, 1.0f);
                    const float slp = fmaf(s, K_INVT, -K_INVT) * wp;
                    float* pi = posAcc + (size_t)gi[r] * 4;
                    atomicAdd(pi + 0, slp);
                    atomicAdd(pi + 1, wp);
                    atomicAdd(pi + 2, we);
                    atomicAdd(pi + 3, 1.0f);
                    if (!diag) {
                        float* pj = posAcc + (size_t)gjr[g] * 4;
                        atomicAdd(pj + 0, slp);
                        atomicAdd(pj + 1, wp);
                        atomicAdd(pj + 2, we);
                        atomicAdd(pj + 3, 1.0f);
                    }
                }
            }
        }
        #pragma unroll
        for (int r = 0; r < 4; r++) {
            #pragma unroll
            for (int off = 1; off < 16; off <<= 1) {
                rd[r] += __shfl_xor(rd[r], off, 64);
                rt[r] += __shfl_xor(rt[r], off, 64);
            }
        }
        if (cl == 0) {
            #pragma unroll
            for (int r = 0; r < 4; r++) {
                const int row = rw * 32 + f * 16 + rg * 4 + r;
                rowDT[cw][row][0] = rd[r];
                rowDT[cw][row][1] = rt[r];
            }
        }
    }
    if (!diag) {
        #pragma unroll
        for (int g = 0; g < 4; g++) {
            cd[g] += __shfl_xor(cd[g], 16, 64);
            cd[g] += __shfl_xor(cd[g], 32, 64);
            ct[g] += __shfl_xor(ct[g], 16, 64);
            ct[g] += __shfl_xor(ct[g], 32, 64);
        }
        if (rg == 0) {
            #pragma unroll
            for (int g = 0; g < 4; g++) {
                const int col = cw * 64 + g * 16 + cl;
                colDT[rw][col][0] = cd[g];
                colDT[rw][col][1] = ct[g];
            }
        }
    }

    __syncthreads();
    if (tid < BM) {
        float2 v;
        v.x = rowDT[0][tid][0] + rowDT[1][tid][0];
        v.y = rowDT[0][tid][1] + rowDT[1][tid][1];
        ((float2*)part)[(size_t)Jt * BSZ + I0 + tid] = v;
    } else if (tid < 2 * BM && !diag) {
        const int c = tid - BM;
        float2 v;
        v.x = colDT[0][c][0] + colDT[1][c][0] + colDT[2][c][0] + colDT[3][c][0];
        v.y = colDT[0][c][1] + colDT[1][c][1] + colDT[2][c][1] + colDT[3][c][1];
        ((float2*)part)[(size_t)It * BSZ + J0 + c] = v;
    }
}

// ---------------- per-row combine + grid-wide final (done-counter) ----------------
__global__ __launch_bounds__(256) void reduce_final_kernel(
    const float* __restrict__ part, const float* __restrict__ posAcc,
    double* __restrict__ partial, unsigned int* __restrict__ counter,
    float* __restrict__ out)
{
    const int i = blockIdx.x * 256 + threadIdx.x;
    float dsum = 0.f, T2 = 0.f;
    const float2* p2 = (const float2*)part;
    #pragma unroll 8
    for (int j = 0; j < NT; j++) {
        const float2 v = p2[(size_t)j * BSZ + i];
        dsum += v.x; T2 += v.y;
    }
    const float4 pa = ((const float4*)posAcc)[i];   // {s1, w1, s2corr, cnt}
    const float s1 = pa.x, w1 = pa.y, s2 = T2 - pa.z, cnt = pa.w;
    const float pc = fmaxf(cnt, 1.0f);
    const float nc = fmaxf(8191.0f - cnt, 1.0f);
    const float ld = logf(dsum);
    const double pos_i = (double)((s1 - ld * w1) / pc);
    const double neg_i = (double)((s2 / dsum) / nc);

    __shared__ double sp[256], sn[256];
    sp[threadIdx.x] = pos_i; sn[threadIdx.x] = neg_i;
    __syncthreads();
    for (int s = 128; s > 0; s >>= 1) {
        if (threadIdx.x < s) {
            sp[threadIdx.x] += sp[threadIdx.x + s];
            sn[threadIdx.x] += sn[threadIdx.x + s];
        }
        __syncthreads();
    }
    __shared__ bool amLast;
    if (threadIdx.x == 0) {
        partial[blockIdx.x * 2 + 0] = sp[0];
        partial[blockIdx.x * 2 + 1] = sn[0];
        __threadfence();
        amLast = (atomicAdd(counter, 1u) == 31u);
    }
    __syncthreads();
    if (amLast) {
        __threadfence();
        const int lane = threadIdx.x;
        double p = 0.0, n = 0.0;
        if (lane < 32) {
            volatile double* vp = (volatile double*)partial;
            p = vp[lane * 2 + 0];
            n = vp[lane * 2 + 1];
        }
        #pragma unroll
        for (int o = 32; o > 0; o >>= 1) { p += __shfl_xor(p, o, 64); n += __shfl_xor(n, o, 64); }
        if (lane == 0) out[0] = (float)(-p / (double)BSZ + 0.3 * (n / (double)BSZ));
    }
}

extern "C" void kernel_launch(void* const* d_in, const int* in_sizes, int n_in,
                              void* d_out, int out_size, void* d_ws, size_t ws_size,
                              hipStream_t stream) {
    const float* feat = (const float*)d_in[0];
    const int* labels = (const int*)d_in[1];
    float* out = (float*)d_out;

    char* ws = (char*)d_ws;
    unsigned short* anchorT = (unsigned short*)ws;                       // 4 MB MFMA-native
    const size_t anchorBytes = (size_t)BSZ * DDIM * sizeof(unsigned short);
    float* part = (float*)(ws + anchorBytes);                            // 64*8192 float2 = 4 MB
    const size_t partBytes = (size_t)NT * BSZ * 2 * sizeof(float);
    float* posAcc = (float*)(ws + anchorBytes + partBytes);              // 128 KB
    const size_t posBytes = (size_t)BSZ * 4 * sizeof(float);
    double* partial = (double*)(ws + anchorBytes + partBytes + posBytes); // 512 B
    unsigned int* counter = (unsigned int*)(ws + anchorBytes + partBytes + posBytes + 512);

    norm_kernel<<<BSZ / 64, 256, 0, stream>>>(feat, anchorT, posAcc, counter);
    simloss_kernel<<<NTRI, 512, 0, stream>>>(anchorT, labels, part, posAcc);
    reduce_final_kernel<<<BSZ / 256, 256, 0, stream>>>(part, posAcc, partial, counter, out);
}